// Round 7
// baseline (160.535 us; speedup 1.0000x reference)
//
#include <hip/hip_runtime.h>

#define B 128
#define N 65536
#define D 512
#define K 5
#define M 256              // D * RATIO
#define GPB 128            // gallery rows per block (kernel1)
#define NBLK1 (N / GPB)    // 512 blocks
#define CHG 16             // g rows per chunk
#define NCHK (GPB / CHG)   // 8

typedef __attribute__((ext_vector_type(8))) short short8;
typedef __attribute__((ext_vector_type(4))) float f32x4;

// pack two fp32 -> one u32 of 2 bf16 (truncation) via v_perm_b32.
__device__ __forceinline__ unsigned int pack_bf2(float lo, float hi) {
    return __builtin_amdgcn_perm(__float_as_uint(hi), __float_as_uint(lo), 0x07060302u);
}

__device__ __forceinline__ void top5_insert(float v, int gi, float tv[K], int ti[K]) {
    // descending by value, ties broken by lower index (matches lax.top_k)
    if (v > tv[K - 1] || (v == tv[K - 1] && gi < ti[K - 1])) {
        tv[K - 1] = v; ti[K - 1] = gi;
        #pragma unroll
        for (int k = K - 1; k > 0; --k) {
            bool sw = (tv[k] > tv[k - 1]) || (tv[k] == tv[k - 1] && ti[k] < ti[k - 1]);
            if (sw) {
                float fv = tv[k]; tv[k] = tv[k - 1]; tv[k - 1] = fv;
                int fi = ti[k]; ti[k] = ti[k - 1]; ti[k - 1] = fi;
            }
        }
    }
}

// Kernel 0: convert t_f (128x512 fp32) -> bf16 once. L2-resident thereafter.
__global__ __launch_bounds__(256) void k0_cvt_t(const float* __restrict__ t_f,
                                                unsigned int* __restrict__ t_bf) {
    int i = blockIdx.x * 256 + threadIdx.x;   // float4 index, 16384 total
    float4 v = reinterpret_cast<const float4*>(t_f)[i];
    uint2 p;
    p.x = pack_bf2(v.x, v.y);
    p.y = pack_bf2(v.z, v.w);
    reinterpret_cast<uint2*>(t_bf)[i] = p;
}

// Kernel 1: bf16 MFMA sims, 8 waves, 128b x 128g per block.
// R6 lesson: the old staging pattern (16 cache lines @ stride 2KB per wave
// instruction) delivered only ~620 GB/s and every chunk barrier exposed full
// latency. Now each wave owns g-rows {2w,2w+1} ENTIRELY: every global load
// instruction is 1KB unit-stride (lane l -> byte l*16). LDS stays k-slice
// major with a ^(bh<<4) XOR applied identically on write and fragment read.
// Depth-2 register prefetch (two named sets, fully unrolled -> no scratch),
// one barrier per chunk, wave-local norms via shfl.
__global__ __launch_bounds__(512) void k1_sims_topk(const unsigned short* __restrict__ t_bf,
                                                    const float* __restrict__ gal,
                                                    float2* __restrict__ partial,
                                                    unsigned long long* __restrict__ mask64,
                                                    unsigned int* __restrict__ counter) {
    __shared__ __align__(16) unsigned short gLds[2][CHG * D];   // 2 x 16384 B
    __shared__ float normP[2][CHG];                             // 128 B

    const int tid = threadIdx.x;
    // XCD-aware swizzle: consecutive-on-XCD blocks read contiguous gallery slabs
    const int blk = (blockIdx.x & 7) * (NBLK1 / 8) + (blockIdx.x >> 3);
    const int lane = tid & 63;
    const int w = tid >> 6;
    const int l15 = lane & 15;
    const int l4 = lane >> 4;
    const int bh = lane >> 3;            // 0..7  (k-slice sub-index of this lane)
    const int colb = (lane & 7) * 8;     // byte col within a slice-row segment
    const int xr = bh << 4;              // write/read XOR swizzle
    const int rb = l15 * 64 + l4 * 16;   // fragment-read byte within slice

    if (blockIdx.x == 0) {
        if (tid < (D / 64)) mask64[tid] = ~0ull;   // init AND bitmap
        if (tid == 8) *counter = 0u;               // completion counter for k23
    }

    // A fragments: wave's 16 b-rows (row = l15), bf16, pinned. 64 VGPRs.
    short8 afr[16];
    {
        const unsigned short* tp = t_bf + (size_t)(w * 16 + l15) * D + l4 * 8;
        #pragma unroll
        for (int ks = 0; ks < 16; ++ks) {
            uint4 q = *reinterpret_cast<const uint4*>(tp + ks * 32);
            asm volatile("" : "+v"(q.x), "+v"(q.y), "+v"(q.z), "+v"(q.w));
            afr[ks] = *reinterpret_cast<short8*>(&q);
        }
    }

    // packed top-5 lists: lst[r] for b-row w*16 + l4*4 + r, over g ≡ l15 (mod 16)
    float lst[4][K];
    #pragma unroll
    for (int r = 0; r < 4; ++r)
        #pragma unroll
        for (int k = 0; k < K; ++k) lst[r][k] = -1e30f;

    // wave-contiguous source: wave w covers rows {2w, 2w+1} fully per chunk
    const float* gbase = gal + ((size_t)blk * GPB + 2 * w) * D + lane * 4;

#define LOADSET(R0, R1, R2, R3, CIDX) do { \
        const float* gp_ = gbase + (size_t)(CIDX) * (CHG * D); \
        R0 = *reinterpret_cast<const float4*>(gp_); \
        R1 = *reinterpret_cast<const float4*>(gp_ + 256); \
        R2 = *reinterpret_cast<const float4*>(gp_ + 512); \
        R3 = *reinterpret_cast<const float4*>(gp_ + 768); \
    } while (0)

    // piece i: ks = (i&1)*8 + bh, r = 2w + (i>>1); byte = ks*1024 + ((r*64+colb)^xr)
#define STAGE(R0, R1, R2, R3, BUFI) do { \
        char* LB_ = reinterpret_cast<char*>(&gLds[BUFI][0]); \
        uint2 q_; \
        q_.x = pack_bf2(R0.x, R0.y); q_.y = pack_bf2(R0.z, R0.w); \
        *reinterpret_cast<uint2*>(LB_ + (bh)      * 1024 + (((2 * w) * 64 + colb) ^ xr)) = q_; \
        q_.x = pack_bf2(R1.x, R1.y); q_.y = pack_bf2(R1.z, R1.w); \
        *reinterpret_cast<uint2*>(LB_ + (8 + bh)  * 1024 + (((2 * w) * 64 + colb) ^ xr)) = q_; \
        q_.x = pack_bf2(R2.x, R2.y); q_.y = pack_bf2(R2.z, R2.w); \
        *reinterpret_cast<uint2*>(LB_ + (bh)      * 1024 + (((2 * w + 1) * 64 + colb) ^ xr)) = q_; \
        q_.x = pack_bf2(R3.x, R3.y); q_.y = pack_bf2(R3.z, R3.w); \
        *reinterpret_cast<uint2*>(LB_ + (8 + bh)  * 1024 + (((2 * w + 1) * 64 + colb) ^ xr)) = q_; \
        float nrA_ = 0.f, nrB_ = 0.f; \
        nrA_ = fmaf(R0.x, R0.x, nrA_); nrA_ = fmaf(R0.y, R0.y, nrA_); \
        nrA_ = fmaf(R0.z, R0.z, nrA_); nrA_ = fmaf(R0.w, R0.w, nrA_); \
        nrA_ = fmaf(R1.x, R1.x, nrA_); nrA_ = fmaf(R1.y, R1.y, nrA_); \
        nrA_ = fmaf(R1.z, R1.z, nrA_); nrA_ = fmaf(R1.w, R1.w, nrA_); \
        nrB_ = fmaf(R2.x, R2.x, nrB_); nrB_ = fmaf(R2.y, R2.y, nrB_); \
        nrB_ = fmaf(R2.z, R2.z, nrB_); nrB_ = fmaf(R2.w, R2.w, nrB_); \
        nrB_ = fmaf(R3.x, R3.x, nrB_); nrB_ = fmaf(R3.y, R3.y, nrB_); \
        nrB_ = fmaf(R3.z, R3.z, nrB_); nrB_ = fmaf(R3.w, R3.w, nrB_); \
        _Pragma("unroll") \
        for (int s_ = 1; s_ < 64; s_ <<= 1) { \
            nrA_ += __shfl_xor(nrA_, s_); \
            nrB_ += __shfl_xor(nrB_, s_); \
        } \
        if (lane == 0) { normP[BUFI][2 * w] = nrA_; normP[BUFI][2 * w + 1] = nrB_; } \
    } while (0)

#define COMPUTE(BUFI, CIDX) do { \
        f32x4 acc0_ = (f32x4)0.f, acc1_ = (f32x4)0.f; \
        const char* LB_ = reinterpret_cast<const char*>(&gLds[BUFI][0]); \
        _Pragma("unroll") \
        for (int ks_ = 0; ks_ < 16; ks_ += 2) { \
            short8 b0_ = *reinterpret_cast<const short8*>(LB_ + ks_ * 1024 + (rb ^ ((ks_ & 7) << 4))); \
            short8 b1_ = *reinterpret_cast<const short8*>(LB_ + (ks_ + 1) * 1024 + (rb ^ (((ks_ + 1) & 7) << 4))); \
            acc0_ = __builtin_amdgcn_mfma_f32_16x16x32_bf16(afr[ks_], b0_, acc0_, 0, 0, 0); \
            acc1_ = __builtin_amdgcn_mfma_f32_16x16x32_bf16(afr[ks_ + 1], b1_, acc1_, 0, 0, 0); \
        } \
        float sc_ = rsqrtf(normP[BUFI][l15]); \
        unsigned meta_ = (unsigned)((CIDX) * CHG + l15); \
        _Pragma("unroll") \
        for (int r_ = 0; r_ < 4; ++r_) { \
            float s_ = (acc0_[r_] + acc1_[r_]) * sc_; \
            float sp_ = __uint_as_float((__float_as_uint(s_) & 0xFFFFFF00u) | meta_); \
            if (sp_ > lst[r_][K - 1]) { \
                lst[r_][K - 1] = sp_; \
                _Pragma("unroll") \
                for (int k_ = K - 1; k_ > 0; --k_) \
                    if (lst[r_][k_] > lst[r_][k_ - 1]) { \
                        float t_ = lst[r_][k_]; lst[r_][k_] = lst[r_][k_ - 1]; lst[r_][k_ - 1] = t_; \
                    } \
            } \
        } \
    } while (0)

    float4 A0, A1, A2, A3, B0, B1, B2, B3;
    LOADSET(A0, A1, A2, A3, 0);
    LOADSET(B0, B1, B2, B3, 1);
    STAGE(A0, A1, A2, A3, 0);
    __syncthreads();

    #pragma unroll
    for (int cc = 0; cc < NCHK; cc += 2) {
        // even iter: chunk cc (buf0); regs B hold chunk cc+1; A free
        if (cc + 2 < NCHK) LOADSET(A0, A1, A2, A3, cc + 2);
        if (cc + 1 < NCHK) STAGE(B0, B1, B2, B3, 1);
        COMPUTE(0, cc);
        __syncthreads();
        // odd iter: chunk cc+1 (buf1); regs A hold chunk cc+2; B free
        if (cc + 3 < NCHK) LOADSET(B0, B1, B2, B3, cc + 3);
        if (cc + 2 < NCHK) STAGE(A0, A1, A2, A3, 0);
        COMPUTE(1, cc + 1);
        __syncthreads();
    }

    // merge the 16 g-residues within each l4 group (lists stay packed)
    #pragma unroll
    for (int mk = 1; mk <= 8; mk <<= 1) {
        #pragma unroll
        for (int r = 0; r < 4; ++r) {
            float inc[K];
            #pragma unroll
            for (int k = 0; k < K; ++k) inc[k] = __shfl_xor(lst[r][k], mk);
            #pragma unroll
            for (int k = 0; k < K; ++k) {
                if (inc[k] > lst[r][K - 1]) {
                    lst[r][K - 1] = inc[k];
                    #pragma unroll
                    for (int q = K - 1; q > 0; --q)
                        if (lst[r][q] > lst[r][q - 1]) {
                            float t2 = lst[r][q]; lst[r][q] = lst[r][q - 1]; lst[r][q - 1] = t2;
                        }
                }
            }
        }
    }

    // writers: lane l15==r writes list r (all 16 lanes of a group converged)
    #pragma unroll
    for (int rr = 0; rr < 4; ++rr) {
        if (l15 == rr) {
            int b = w * 16 + l4 * 4 + rr;
            #pragma unroll
            for (int k = 0; k < K; ++k) {
                unsigned sp = __float_as_uint(lst[rr][k]);
                int g = blk * GPB + (int)(sp & 0xFFu);
                partial[((size_t)b * NBLK1 + blk) * K + k] = make_float2(lst[rr][k], __int_as_float(g));
            }
        }
    }
#undef LOADSET
#undef STAGE
#undef COMPUTE
}

// Kernel 23 (fused merge + membership + final mask): block b merges its 512
// partial top-5 lists -> top-5 global rows, computes bottom-m membership of
// |gal[row,c]*s_f[b,c]| per row (per-row norms are positive constants ->
// ordering matches the reference's normalized products), ANDs into the global
// bitmap; the LAST block to finish emits the output mask. Rank scan uses
// float4 LDS reads (4x fewer LDS instructions than R6's scalar scan).
__global__ __launch_bounds__(512) void k23_merge_member(const float2* __restrict__ partial,
                                                        const float* __restrict__ s_f,
                                                        const float* __restrict__ gal,
                                                        unsigned long long* __restrict__ mask64,
                                                        unsigned int* __restrict__ counter,
                                                        float* __restrict__ out) {
    __shared__ float2 cand[NBLK1 * K];          // 20480 B
    __shared__ int idxS[K];
    __shared__ __align__(16) float pS[D];
    __shared__ unsigned long long andW[D / 64];
    __shared__ unsigned long long maskLds[D / 64];
    __shared__ int isLast;

    const int b = blockIdx.x;
    const int p = threadIdx.x;
    if (p < (D / 64)) andW[p] = ~0ull;

    float mv[K]; int mi[K];
    #pragma unroll
    for (int k = 0; k < K; ++k) {
        float2 c = partial[((size_t)b * NBLK1 + p) * K + k];
        mv[k] = c.x; mi[k] = __float_as_int(c.y);
        cand[p * K + k] = c;
    }
    __syncthreads();
    for (int s = NBLK1 / 2; s >= 1; s >>= 1) {
        if (p < s) {
            #pragma unroll
            for (int k = 0; k < K; ++k) {
                float2 c = cand[(p + s) * K + k];
                top5_insert(c.x, __float_as_int(c.y), mv, mi);
            }
            #pragma unroll
            for (int k = 0; k < K; ++k)
                cand[p * K + k] = make_float2(mv[k], __int_as_float(mi[k]));
        }
        __syncthreads();
    }
    if (p == 0) {
        #pragma unroll
        for (int k = 0; k < K; ++k) idxS[k] = mi[k];
    }
    __syncthreads();

    const float sv = s_f[(size_t)b * D + p];
    for (int k = 0; k < K; ++k) {
        const int row = idxS[k];
        float pv = fabsf(gal[(size_t)row * D + p] * sv);
        __syncthreads();          // guard pS reuse from previous iteration
        pS[p] = pv;
        __syncthreads();
        int cnt = 0;
        const float4* p4 = reinterpret_cast<const float4*>(pS);
        #pragma unroll 4
        for (int j = 0; j < D / 4; ++j) {
            float4 o = p4[j];
            cnt += (o.x < pv || (o.x == pv && (4 * j + 0) < p)) ? 1 : 0;
            cnt += (o.y < pv || (o.y == pv && (4 * j + 1) < p)) ? 1 : 0;
            cnt += (o.z < pv || (o.z == pv && (4 * j + 2) < p)) ? 1 : 0;
            cnt += (o.w < pv || (o.w == pv && (4 * j + 3) < p)) ? 1 : 0;
        }
        unsigned long long bm = __ballot(cnt < M);
        if ((p & 63) == 0) andW[p >> 6] &= bm;
    }
    __syncthreads();
    if (p < (D / 64)) atomicAnd(&mask64[p], andW[p]);
    __syncthreads();
    if (p == 0) {
        __threadfence();
        unsigned done = atomicAdd(counter, 1u);
        isLast = (done == B - 1) ? 1 : 0;
    }
    __syncthreads();
    if (isLast) {
        if (p < (D / 64)) {
            __threadfence();
            maskLds[p] = atomicAnd(&mask64[p], ~0ull);   // coherent read
        }
        __syncthreads();
        out[p] = ((maskLds[p >> 6] >> (p & 63)) & 1ull) ? 0.0f : 1.0f;
    }
}

extern "C" void kernel_launch(void* const* d_in, const int* in_sizes, int n_in,
                              void* d_out, int out_size, void* d_ws, size_t ws_size,
                              hipStream_t stream) {
    (void)in_sizes; (void)n_in; (void)out_size; (void)ws_size;
    const float* s_f = (const float*)d_in[0];
    const float* t_f = (const float*)d_in[1];
    const float* gal = (const float*)d_in[2];
    float* out = (float*)d_out;

    char* ws = (char*)d_ws;
    size_t off_tbf = 0;
    size_t sz_tbf = (size_t)B * D * 2;                            // 131072 B
    size_t off_partial = off_tbf + sz_tbf;
    size_t sz_partial = (size_t)NBLK1 * B * K * sizeof(float2);   // 2,621,440 B
    size_t off_mask = off_partial + sz_partial;
    size_t off_cnt = off_mask + (D / 64) * sizeof(unsigned long long);

    unsigned int* t_bf = (unsigned int*)(ws + off_tbf);
    float2* partial = (float2*)(ws + off_partial);
    unsigned long long* mask64 = (unsigned long long*)(ws + off_mask);
    unsigned int* counter = (unsigned int*)(ws + off_cnt);

    hipLaunchKernelGGL(k0_cvt_t, dim3(B * D / 4 / 256), dim3(256), 0, stream, t_f, t_bf);
    hipLaunchKernelGGL(k1_sims_topk, dim3(NBLK1), dim3(512), 0, stream,
                       (const unsigned short*)t_bf, gal, partial, mask64, counter);
    hipLaunchKernelGGL(k23_merge_member, dim3(B), dim3(512), 0, stream,
                       partial, s_f, gal, mask64, counter, out);
}